// Round 12
// baseline (686.185 us; speedup 1.0000x reference)
//
#include <hip/hip_runtime.h>
#include <hip/hip_bf16.h>
#include <cstddef>

// Problem constants
#define N_NODES 4096
#define DIM     128
#define NHEAD   2
#define DHEAD   64
#define FFDIM   256
#define NEDGE   2048
#define NNZ_E   65536
#define NSPLIT  8
#define HG_BLOCKS 512

typedef __attribute__((ext_vector_type(8))) short bf16x8;   // 8 bf16 in 4 VGPRs
typedef __attribute__((ext_vector_type(4))) float f32x4;
typedef unsigned short u16;

__device__ __forceinline__ u16 f2b(float f) {               // rne fp32->bf16
    unsigned u = __float_as_uint(f);
    return (u16)((u + 0x7FFFu + ((u >> 16) & 1u)) >> 16);
}
__device__ __forceinline__ float b2f_bits(u16 h) {
    return __uint_as_float(((unsigned)h) << 16);
}

// ---------------------------------------------------------------------------
// prep: blocks [0,2048) split x; [2048,2944) pack weights; [2944,2969) zero
// cnt_e+cnt_n+barrier slots (6160 ints).
__global__ void prep(const float* __restrict__ x, float* __restrict__ h,
                     u16* __restrict__ hh, u16* __restrict__ hl,
                     const float* W0, const float* W1, const float* W2,
                     const float* W3, const float* W4, const float* W5,
                     const float* W6,
                     u16* P0, u16* P1, u16* P2, u16* P3, u16* P4, u16* P5, u16* P6,
                     int* __restrict__ cnt) {
    const int bx = blockIdx.x;
    if (bx < 2048) {
        int i = bx * 256 + threadIdx.x;
        float f = x[i];
        h[i] = f;
        u16 hi = f2b(f);
        hh[i] = hi;
        hl[i] = f2b(f - b2f_bits(hi));
        return;
    }
    if (bx >= 2944) {                 // zero cnt_e+cnt_n+bar (6160 ints)
        int i = (bx - 2944) * 256 + threadIdx.x;
        if (i < NEDGE + N_NODES + 16) cnt[i] = 0;
        return;
    }
    const int p = bx - 2048;
    const int sel = p >> 7;
    const float* W; u16* P; int K, NC;
    switch (sel) {
        case 0: W = W0; P = P0; K = 128; NC = 128; break;
        case 1: W = W1; P = P1; K = 128; NC = 128; break;
        case 2: W = W2; P = P2; K = 128; NC = 128; break;
        case 3: W = W3; P = P3; K = 128; NC = 128; break;
        case 4: W = W4; P = P4; K = 128; NC = 128; break;
        case 5: W = W5; P = P5; K = 128; NC = 256; break;
        default: W = W6; P = P6; K = 256; NC = 128; break;
    }
    int i = (p & 127) * 256 + threadIdx.x;
    if (i < K * NC) {
        int k = i / NC, n = i % NC;
        float f = W[i];
        u16 hb = f2b(f);
        size_t o = ((size_t)(k >> 3) * NC + n) * 8 + (k & 7);
        P[o] = hb;
        P[(size_t)K * NC + o] = f2b(f - b2f_bits(hb));
    }
}

// ---------------------------------------------------------------------------
// Fused QKV GEMM (layer 1 only). Grid (64, 12): sel = y>>2, col0 = (y&3)*32.
__global__ __launch_bounds__(256) void qkv_mfma(const u16* __restrict__ Ah,
                                                const u16* __restrict__ Al,
                                                const u16* __restrict__ Wq,
                                                const u16* __restrict__ Wk,
                                                const u16* __restrict__ Wv,
                                                const float* __restrict__ bq,
                                                const float* __restrict__ bk,
                                                const float* __restrict__ bv,
                                                u16* __restrict__ qb,
                                                u16* __restrict__ kb,
                                                u16* __restrict__ vtb) {
    const int K = 128, NC = 128;
    const int tid = threadIdx.x, w = tid >> 6, lane = tid & 63;
    const int qi = lane & 15, gi = lane >> 4;
    const int row0 = blockIdx.x * 64 + w * 16;
    const int sel = blockIdx.y >> 2;
    const int col0 = (blockIdx.y & 3) * 32;
    const u16* Wp = (sel == 0) ? Wq : (sel == 1) ? Wk : Wv;
    const float* bias = (sel == 0) ? bq : (sel == 1) ? bk : bv;
    const u16* Wlo = Wp + (size_t)K * NC;

    f32x4 acc[2];
    acc[0] = (f32x4){0.f, 0.f, 0.f, 0.f};
    acc[1] = (f32x4){0.f, 0.f, 0.f, 0.f};

#pragma unroll 4
    for (int kc = 0; kc < K / 32; ++kc) {
        const int k0 = kc * 32;
        const size_t ao = (size_t)(row0 + qi) * K + k0 + gi * 8;
        bf16x8 ah = *(const bf16x8*)(Ah + ao);
        bf16x8 al = *(const bf16x8*)(Al + ao);
#pragma unroll
        for (int c = 0; c < 2; ++c) {
            const size_t wo = ((size_t)(k0 / 8 + gi) * NC + col0 + c * 16 + qi) * 8;
            bf16x8 wh = *(const bf16x8*)(Wp + wo);
            bf16x8 wl = *(const bf16x8*)(Wlo + wo);
            acc[c] = __builtin_amdgcn_mfma_f32_16x16x32_bf16(ah, wh, acc[c], 0, 0, 0);
            acc[c] = __builtin_amdgcn_mfma_f32_16x16x32_bf16(al, wh, acc[c], 0, 0, 0);
            acc[c] = __builtin_amdgcn_mfma_f32_16x16x32_bf16(ah, wl, acc[c], 0, 0, 0);
        }
    }

#pragma unroll
    for (int c = 0; c < 2; ++c) {
        const int col = col0 + c * 16 + qi;
        const int hh = col >> 6, d = col & 63;
        float bv_ = bias[col];
        if (sel < 2) {
            u16* dst = (sel == 0) ? qb : kb;
#pragma unroll
            for (int r = 0; r < 4; ++r) {
                const int grow = row0 + gi * 4 + r;
                dst[((size_t)hh * N_NODES + grow) * 64 + d] = f2b(acc[c][r] + bv_);
            }
        } else {
            const int grow0 = row0 + gi * 4;
            ushort4 pw;
            pw.x = f2b(acc[c][0] + bv_);
            pw.y = f2b(acc[c][1] + bv_);
            pw.z = f2b(acc[c][2] + bv_);
            pw.w = f2b(acc[c][3] + bv_);
            *(ushort4*)&vtb[((size_t)hh * 64 + d) * N_NODES + grow0] = pw;
        }
    }
}

// ---------------------------------------------------------------------------
// Split-K MFMA flash attention. Grid (N/64, H, NSPLIT); block 256 = 4 waves.
#define ROWP 72
__global__ __launch_bounds__(256) void attn_mfma(const u16* __restrict__ qb,
                                                 const u16* __restrict__ kb,
                                                 const u16* __restrict__ vtb,
                                                 float* __restrict__ op,
                                                 float* __restrict__ mlm,
                                                 float* __restrict__ mll) {
    __shared__ __align__(16) u16 k_s[64 * ROWP];
    __shared__ __align__(16) u16 vt_s[64 * ROWP];
    __shared__ __align__(16) u16 p_s[4][16 * ROWP];
    const int h = blockIdx.y;
    const int s = blockIdx.z;
    const int row0 = blockIdx.x * 64;
    const int tid = threadIdx.x;
    const int w = tid >> 6, lane = tid & 63;
    const int qi = lane & 15, gi = lane >> 4;
    const float CE = 0.18033688011f;   // 0.125 * log2(e)

    const u16* qrow = qb + ((size_t)h * N_NODES + row0 + w * 16 + qi) * 64 + gi * 8;
    bf16x8 qf0 = *(const bf16x8*)qrow;
    bf16x8 qf1 = *(const bf16x8*)(qrow + 32);

    f32x4 oc[4];
#pragma unroll
    for (int i = 0; i < 4; ++i) oc[i] = (f32x4){0.f, 0.f, 0.f, 0.f};
    float m_run = -INFINITY, l_run = 0.f;

    const u16* kbh = kb + (size_t)h * N_NODES * 64;
    const u16* vth = vtb + (size_t)h * 64 * N_NODES;

    for (int kt = s * (N_NODES / 64 / NSPLIT); kt < (s + 1) * (N_NODES / 64 / NSPLIT); ++kt) {
        const u16* ksrc = kbh + kt * 64 * 64;
#pragma unroll
        for (int i = 0; i < 2; ++i) {
            int c = tid + i * 256;
            int r = c >> 3, ss = c & 7;
            *(uint4*)&k_s[r * ROWP + ss * 8]  = *(const uint4*)(ksrc + c * 8);
            *(uint4*)&vt_s[r * ROWP + ss * 8] = *(const uint4*)(vth + (size_t)r * N_NODES + kt * 64 + ss * 8);
        }
        __syncthreads();

        f32x4 sc[4];
#pragma unroll
        for (int t = 0; t < 4; ++t) {
            const u16* krow = &k_s[(t * 16 + qi) * ROWP + gi * 8];
            bf16x8 ka0 = *(const bf16x8*)krow;
            bf16x8 ka1 = *(const bf16x8*)(krow + 32);
            f32x4 z = (f32x4){0.f, 0.f, 0.f, 0.f};
            z = __builtin_amdgcn_mfma_f32_16x16x32_bf16(ka0, qf0, z, 0, 0, 0);
            sc[t] = __builtin_amdgcn_mfma_f32_16x16x32_bf16(ka1, qf1, z, 0, 0, 0);
        }

        float smax = -INFINITY;
#pragma unroll
        for (int t = 0; t < 4; ++t)
            smax = fmaxf(smax, fmaxf(fmaxf(sc[t][0], sc[t][1]), fmaxf(sc[t][2], sc[t][3])));
        smax = fmaxf(smax, __shfl_xor(smax, 16));
        smax = fmaxf(smax, __shfl_xor(smax, 32));
        float mn = fmaxf(m_run, smax);
        float alpha = exp2f((m_run - mn) * CE);
        m_run = mn;
        float nb = mn * CE;
        float psum = 0.f;
#pragma unroll
        for (int t = 0; t < 4; ++t) {
            ushort4 pw;
            float p0 = exp2f(fmaf(sc[t][0], CE, -nb)); psum += p0; pw.x = f2b(p0);
            float p1 = exp2f(fmaf(sc[t][1], CE, -nb)); psum += p1; pw.y = f2b(p1);
            float p2 = exp2f(fmaf(sc[t][2], CE, -nb)); psum += p2; pw.z = f2b(p2);
            float p3 = exp2f(fmaf(sc[t][3], CE, -nb)); psum += p3; pw.w = f2b(p3);
            *(ushort4*)&p_s[w][qi * ROWP + t * 16 + gi * 4] = pw;
        }
        psum += __shfl_xor(psum, 16);
        psum += __shfl_xor(psum, 32);
        l_run = l_run * alpha + psum;

        float a0 = __shfl(alpha, gi * 4 + 0);
        float a1 = __shfl(alpha, gi * 4 + 1);
        float a2 = __shfl(alpha, gi * 4 + 2);
        float a3 = __shfl(alpha, gi * 4 + 3);
#pragma unroll
        for (int d = 0; d < 4; ++d) {
            oc[d][0] *= a0; oc[d][1] *= a1; oc[d][2] *= a2; oc[d][3] *= a3;
        }

        const u16* prow = &p_s[w][qi * ROWP];
        bf16x8 pa0 = *(const bf16x8*)(prow + gi * 8);
        bf16x8 pa1 = *(const bf16x8*)(prow + 32 + gi * 8);
#pragma unroll
        for (int d = 0; d < 4; ++d) {
            const u16* vrow = &vt_s[(d * 16 + qi) * ROWP + gi * 8];
            bf16x8 vb0 = *(const bf16x8*)vrow;
            bf16x8 vb1 = *(const bf16x8*)(vrow + 32);
            oc[d] = __builtin_amdgcn_mfma_f32_16x16x32_bf16(pa0, vb0, oc[d], 0, 0, 0);
            oc[d] = __builtin_amdgcn_mfma_f32_16x16x32_bf16(pa1, vb1, oc[d], 0, 0, 0);
        }
        __syncthreads();
    }

    float* opd = op + (size_t)s * N_NODES * 128;
#pragma unroll
    for (int d = 0; d < 4; ++d) {
        size_t cb = h * 64 + d * 16 + qi;
        opd[(size_t)(row0 + w * 16 + gi * 4 + 0) * 128 + cb] = oc[d][0];
        opd[(size_t)(row0 + w * 16 + gi * 4 + 1) * 128 + cb] = oc[d][1];
        opd[(size_t)(row0 + w * 16 + gi * 4 + 2) * 128 + cb] = oc[d][2];
        opd[(size_t)(row0 + w * 16 + gi * 4 + 3) * 128 + cb] = oc[d][3];
    }
    if (gi == 0) {
        size_t mi = (size_t)s * NHEAD * N_NODES + (size_t)h * N_NODES + row0 + w * 16 + qi;
        mlm[mi] = m_run;
        mll[mi] = l_run;
    }
}

// ---------------------------------------------------------------------------
// MEGA layer tail (unchanged from R11): combine -> Wo -> LN1 -> FF -> LN2 -> h
// (+ optional next-layer QKV).
#define ROWA 136
#define ROWZ 264
#define ROWH 132
template<int DO_QKV>
__global__ __launch_bounds__(256) void mega_layer(
        const float* __restrict__ op, const float* __restrict__ mlm,
        const float* __restrict__ mll,
        const u16* __restrict__ wp_o, const float* __restrict__ bo,
        float* __restrict__ h,
        const float* __restrict__ g1, const float* __restrict__ b1,
        const u16* __restrict__ wp_1, const float* __restrict__ bf1,
        const u16* __restrict__ wp_2, const float* __restrict__ bf2,
        const float* __restrict__ g2, const float* __restrict__ b2,
        const u16* __restrict__ wp_q, const u16* __restrict__ wp_k,
        const u16* __restrict__ wp_v,
        const float* __restrict__ bq, const float* __restrict__ bk,
        const float* __restrict__ bv,
        u16* __restrict__ qb, u16* __restrict__ kb, u16* __restrict__ vtb) {
    __shared__ __align__(16) u16 zbuf[16 * ROWZ * 2];
    __shared__ __align__(16) u16 hp_hi[16 * ROWA];
    __shared__ __align__(16) u16 hp_lo[16 * ROWA];
    __shared__ float hln[16 * ROWH];
    __shared__ float ws_s[NSPLIT][32];
    __shared__ float Linv_s[32];
    __shared__ float wsum[4][16], wsq[4][16];
    const float CE = 0.18033688011f;
    const int tid = threadIdx.x, w = tid >> 6, lane = tid & 63;
    const int qi = lane & 15, gi = lane >> 4;
    const int row0 = blockIdx.x * 16;
    u16* a_hi = zbuf;
    u16* a_lo = zbuf + 16 * ROWA;
    u16* z_hi = zbuf;
    u16* z_lo = zbuf + 16 * ROWZ;

    if (tid < 32) {
        int r = tid >> 1, hd = tid & 1;
        size_t mb = (size_t)hd * N_NODES + row0 + r;
        float m[NSPLIT], l[NSPLIT], mx = -INFINITY;
#pragma unroll
        for (int s = 0; s < NSPLIT; ++s) {
            m[s] = mlm[mb + (size_t)s * NHEAD * N_NODES];
            l[s] = mll[mb + (size_t)s * NHEAD * N_NODES];
            mx = fmaxf(mx, m[s]);
        }
        float L = 0.f;
#pragma unroll
        for (int s = 0; s < NSPLIT; ++s) {
            float ws = exp2f((m[s] - mx) * CE);
            ws_s[s][tid] = ws;
            L += ws * l[s];
        }
        Linv_s[tid] = 1.f / L;
    }
    __syncthreads();

    for (int e = tid; e < 16 * 128; e += 256) {
        int r = e >> 7, c = e & 127, hd = c >> 6;
        size_t idx = (size_t)(row0 + r) * 128 + c;
        float O = 0.f;
#pragma unroll
        for (int s = 0; s < NSPLIT; ++s)
            O += ws_s[s][r * 2 + hd] * op[(size_t)s * N_NODES * 128 + idx];
        float v = O * Linv_s[r * 2 + hd];
        u16 hi = f2b(v);
        a_hi[r * ROWA + c] = hi;
        a_lo[r * ROWA + c] = f2b(v - b2f_bits(hi));
    }
    __syncthreads();

    {
        const u16* Wlo = wp_o + (size_t)128 * 128;
        f32x4 acc[2];
        acc[0] = (f32x4){0.f, 0.f, 0.f, 0.f};
        acc[1] = (f32x4){0.f, 0.f, 0.f, 0.f};
        const int col0 = w * 32;
#pragma unroll
        for (int kc = 0; kc < 4; ++kc) {
            const int k0 = kc * 32;
            bf16x8 ah = *(const bf16x8*)&a_hi[qi * ROWA + k0 + gi * 8];
            bf16x8 al = *(const bf16x8*)&a_lo[qi * ROWA + k0 + gi * 8];
#pragma unroll
            for (int c = 0; c < 2; ++c) {
                const size_t wo = ((size_t)(k0 / 8 + gi) * 128 + col0 + c * 16 + qi) * 8;
                bf16x8 wh = *(const bf16x8*)(wp_o + wo);
                bf16x8 wl = *(const bf16x8*)(Wlo + wo);
                acc[c] = __builtin_amdgcn_mfma_f32_16x16x32_bf16(ah, wh, acc[c], 0, 0, 0);
                acc[c] = __builtin_amdgcn_mfma_f32_16x16x32_bf16(al, wh, acc[c], 0, 0, 0);
                acc[c] = __builtin_amdgcn_mfma_f32_16x16x32_bf16(ah, wl, acc[c], 0, 0, 0);
            }
        }
        float y[2][4], rs[4], rq[4];
#pragma unroll
        for (int r = 0; r < 4; ++r) { rs[r] = 0.f; rq[r] = 0.f; }
#pragma unroll
        for (int c = 0; c < 2; ++c) {
            const int col = col0 + c * 16 + qi;
            float bv = bo[col];
#pragma unroll
            for (int r = 0; r < 4; ++r) {
                float v = acc[c][r] + bv + h[(size_t)(row0 + gi * 4 + r) * 128 + col];
                y[c][r] = v;
                rs[r] += v; rq[r] += v * v;
            }
        }
#pragma unroll
        for (int r = 0; r < 4; ++r)
            for (int msk = 1; msk < 16; msk <<= 1) {
                rs[r] += __shfl_xor(rs[r], msk);
                rq[r] += __shfl_xor(rq[r], msk);
            }
        if (qi == 0) {
#pragma unroll
            for (int r = 0; r < 4; ++r) { wsum[w][gi * 4 + r] = rs[r]; wsq[w][gi * 4 + r] = rq[r]; }
        }
        __syncthreads();
#pragma unroll
        for (int r = 0; r < 4; ++r) {
            const int lr = gi * 4 + r;
            float ts = wsum[0][lr] + wsum[1][lr] + wsum[2][lr] + wsum[3][lr];
            float tq = wsq[0][lr] + wsq[1][lr] + wsq[2][lr] + wsq[3][lr];
            float mean = ts * (1.f / 128.f);
            float var  = tq * (1.f / 128.f) - mean * mean;
            float rstd = rsqrtf(var + 1e-5f);
#pragma unroll
            for (int c = 0; c < 2; ++c) {
                const int col = col0 + c * 16 + qi;
                float yn = (y[c][r] - mean) * rstd * g1[col] + b1[col];
                hln[lr * ROWH + col] = yn;
                u16 hi = f2b(yn);
                hp_hi[lr * ROWA + col] = hi;
                hp_lo[lr * ROWA + col] = f2b(yn - b2f_bits(hi));
            }
        }
    }
    __syncthreads();

    {
        const u16* W1lo = wp_1 + (size_t)128 * 256;
        f32x4 acc1[4];
#pragma unroll
        for (int t = 0; t < 4; ++t) acc1[t] = (f32x4){0.f, 0.f, 0.f, 0.f};
#pragma unroll
        for (int kc = 0; kc < 4; ++kc) {
            const int k0 = kc * 32;
            bf16x8 ah = *(const bf16x8*)&hp_hi[qi * ROWA + k0 + gi * 8];
            bf16x8 al = *(const bf16x8*)&hp_lo[qi * ROWA + k0 + gi * 8];
#pragma unroll
            for (int t = 0; t < 4; ++t) {
                const size_t wo = ((size_t)(k0 / 8 + gi) * 256 + w * 64 + t * 16 + qi) * 8;
                bf16x8 wh = *(const bf16x8*)(wp_1 + wo);
                bf16x8 wl = *(const bf16x8*)(W1lo + wo);
                acc1[t] = __builtin_amdgcn_mfma_f32_16x16x32_bf16(ah, wh, acc1[t], 0, 0, 0);
                acc1[t] = __builtin_amdgcn_mfma_f32_16x16x32_bf16(al, wh, acc1[t], 0, 0, 0);
                acc1[t] = __builtin_amdgcn_mfma_f32_16x16x32_bf16(ah, wl, acc1[t], 0, 0, 0);
            }
        }
        __syncthreads();
#pragma unroll
        for (int t = 0; t < 4; ++t) {
            const int col = w * 64 + t * 16 + qi;
            float bv = bf1[col];
#pragma unroll
            for (int r = 0; r < 4; ++r) {
                float v = acc1[t][r] + bv;
                v = 1.f / (1.f + __expf(-v));
                u16 hi = f2b(v);
                const int zr = gi * 4 + r;
                z_hi[zr * ROWZ + col] = hi;
                z_lo[zr * ROWZ + col] = f2b(v - b2f_bits(hi));
            }
        }
    }
    __syncthreads();

    {
        const u16* W2lo = wp_2 + (size_t)256 * 128;
        f32x4 acc[2];
        acc[0] = (f32x4){0.f, 0.f, 0.f, 0.f};
        acc[1] = (f32x4){0.f, 0.f, 0.f, 0.f};
        const int col0 = w * 32;
#pragma unroll
        for (int kc = 0; kc < 8; ++kc) {
            const int k0 = kc * 32;
            bf16x8 ah = *(const bf16x8*)&z_hi[qi * ROWZ + k0 + gi * 8];
            bf16x8 al = *(const bf16x8*)&z_lo[qi * ROWZ + k0 + gi * 8];
#pragma unroll
            for (int c = 0; c < 2; ++c) {
                const size_t wo = ((size_t)(k0 / 8 + gi) * 128 + col0 + c * 16 + qi) * 8;
                bf16x8 wh = *(const bf16x8*)(wp_2 + wo);
                bf16x8 wl = *(const bf16x8*)(W2lo + wo);
                acc[c] = __builtin_amdgcn_mfma_f32_16x16x32_bf16(ah, wh, acc[c], 0, 0, 0);
                acc[c] = __builtin_amdgcn_mfma_f32_16x16x32_bf16(al, wh, acc[c], 0, 0, 0);
                acc[c] = __builtin_amdgcn_mfma_f32_16x16x32_bf16(ah, wl, acc[c], 0, 0, 0);
            }
        }
        float y[2][4], rs[4], rq[4];
#pragma unroll
        for (int r = 0; r < 4; ++r) { rs[r] = 0.f; rq[r] = 0.f; }
#pragma unroll
        for (int c = 0; c < 2; ++c) {
            const int col = col0 + c * 16 + qi;
            float bv = bf2[col];
#pragma unroll
            for (int r = 0; r < 4; ++r) {
                float v = acc[c][r] + bv + hln[(gi * 4 + r) * ROWH + col];
                y[c][r] = v;
                rs[r] += v; rq[r] += v * v;
            }
        }
#pragma unroll
        for (int r = 0; r < 4; ++r)
            for (int msk = 1; msk < 16; msk <<= 1) {
                rs[r] += __shfl_xor(rs[r], msk);
                rq[r] += __shfl_xor(rq[r], msk);
            }
        if (qi == 0) {
#pragma unroll
            for (int r = 0; r < 4; ++r) { wsum[w][gi * 4 + r] = rs[r]; wsq[w][gi * 4 + r] = rq[r]; }
        }
        __syncthreads();
#pragma unroll
        for (int r = 0; r < 4; ++r) {
            const int lr = gi * 4 + r;
            float ts = wsum[0][lr] + wsum[1][lr] + wsum[2][lr] + wsum[3][lr];
            float tq = wsq[0][lr] + wsq[1][lr] + wsq[2][lr] + wsq[3][lr];
            float mean = ts * (1.f / 128.f);
            float var  = tq * (1.f / 128.f) - mean * mean;
            float rstd = rsqrtf(var + 1e-5f);
#pragma unroll
            for (int c = 0; c < 2; ++c) {
                const int col = col0 + c * 16 + qi;
                float yn = (y[c][r] - mean) * rstd * g2[col] + b2[col];
                h[(size_t)(row0 + lr) * 128 + col] = yn;
                if (DO_QKV) {
                    u16 hi = f2b(yn);
                    hp_hi[lr * ROWA + col] = hi;
                    hp_lo[lr * ROWA + col] = f2b(yn - b2f_bits(hi));
                }
            }
        }
    }

    if (DO_QKV) {
        __syncthreads();
        const int col0 = w * 32;
#pragma unroll
        for (int sel = 0; sel < 3; ++sel) {
            const u16* Wp = (sel == 0) ? wp_q : (sel == 1) ? wp_k : wp_v;
            const float* bias = (sel == 0) ? bq : (sel == 1) ? bk : bv;
            const u16* Wlo = Wp + (size_t)128 * 128;
            f32x4 acc[2];
            acc[0] = (f32x4){0.f, 0.f, 0.f, 0.f};
            acc[1] = (f32x4){0.f, 0.f, 0.f, 0.f};
#pragma unroll
            for (int kc = 0; kc < 4; ++kc) {
                const int k0 = kc * 32;
                bf16x8 ah = *(const bf16x8*)&hp_hi[qi * ROWA + k0 + gi * 8];
                bf16x8 al = *(const bf16x8*)&hp_lo[qi * ROWA + k0 + gi * 8];
#pragma unroll
                for (int c = 0; c < 2; ++c) {
                    const size_t wo = ((size_t)(k0 / 8 + gi) * 128 + col0 + c * 16 + qi) * 8;
                    bf16x8 wh = *(const bf16x8*)(Wp + wo);
                    bf16x8 wl = *(const bf16x8*)(Wlo + wo);
                    acc[c] = __builtin_amdgcn_mfma_f32_16x16x32_bf16(ah, wh, acc[c], 0, 0, 0);
                    acc[c] = __builtin_amdgcn_mfma_f32_16x16x32_bf16(al, wh, acc[c], 0, 0, 0);
                    acc[c] = __builtin_amdgcn_mfma_f32_16x16x32_bf16(ah, wl, acc[c], 0, 0, 0);
                }
            }
#pragma unroll
            for (int c = 0; c < 2; ++c) {
                const int col = col0 + c * 16 + qi;
                const int hh = col >> 6, d = col & 63;
                float bv_ = bias[col];
                if (sel < 2) {
                    u16* dst = (sel == 0) ? qb : kb;
#pragma unroll
                    for (int r = 0; r < 4; ++r) {
                        const int grow = row0 + gi * 4 + r;
                        dst[((size_t)hh * N_NODES + grow) * 64 + d] = f2b(acc[c][r] + bv_);
                    }
                } else {
                    const int grow0 = row0 + gi * 4;
                    ushort4 pw;
                    pw.x = f2b(acc[c][0] + bv_);
                    pw.y = f2b(acc[c][1] + bv_);
                    pw.z = f2b(acc[c][2] + bv_);
                    pw.w = f2b(acc[c][3] + bv_);
                    *(ushort4*)&vtb[((size_t)hh * 64 + d) * N_NODES + grow0] = pw;
                }
            }
        }
    }
}

// ---------------------------------------------------------------------------
// Hypergraph megakernel: hist -> scan -> fill -> gather_e -> Wh GEMM -> gather_n
// in ONE launch. Grid 512 x 256, __launch_bounds__(256,2): co-residency
// guaranteed (LDS 16.5 KB -> 9 blocks/CU; VGPR capped) so a manual grid
// barrier (device-scope atomics + fences, one slot per barrier, zeroed by
// prep) is valid.
__device__ __forceinline__ void gbar(int* bar, int idx, int nblk) {
    __syncthreads();
    if (threadIdx.x == 0) {
        __threadfence();                              // release: block's stores visible
        atomicAdd(&bar[idx], 1);                      // device-scope
        while (__hip_atomic_load(&bar[idx], __ATOMIC_ACQUIRE,
                                 __HIP_MEMORY_SCOPE_AGENT) < nblk) {}
    }
    __syncthreads();
    __threadfence();                                  // acquire: see other blocks' stores
}

__global__ __launch_bounds__(256, 2) void hyper_mega(
        const int* __restrict__ edge_raw,
        int* __restrict__ nidx, int* __restrict__ hidx,
        int* __restrict__ cnt_e, int* __restrict__ cnt_n,
        int* __restrict__ off_e, int* __restrict__ off_n,
        int* __restrict__ cur_e, int* __restrict__ cur_n,
        int* __restrict__ csr_e, int* __restrict__ csr_n,
        const float* __restrict__ h,
        u16* __restrict__ e_hi, u16* __restrict__ e_lo,
        const u16* __restrict__ wp_h, float* __restrict__ e_sc,
        const float* __restrict__ bh, float* __restrict__ out,
        int* __restrict__ bar) {
    __shared__ int smem[N_NODES];        // 16 KB, reused across phases
    __shared__ int is64_s;
    const int tid = threadIdx.x;
    const int gidx = blockIdx.x * 256 + tid;

    // ---- P0: decode + histogram; zero cur
    if (tid < 64) {
        int v = edge_raw[2 * tid + 1];
        unsigned long long bal = __ballot(v != 0);
        if (tid == 0) is64_s = (bal == 0ull) ? 1 : 0;
    }
    __syncthreads();
    const int is64 = is64_s;
    if (gidx < NNZ_E) {
        int ni = (is64 ? edge_raw[2 * gidx]             : edge_raw[gidx])         & (N_NODES - 1);
        int he = (is64 ? edge_raw[2 * NNZ_E + 2 * gidx] : edge_raw[NNZ_E + gidx]) & (NEDGE - 1);
        nidx[gidx] = ni;
        hidx[gidx] = he;
        atomicAdd(&cnt_n[ni], 1);
        atomicAdd(&cnt_e[he], 1);
    }
    if (gidx < NEDGE) cur_e[gidx] = 0;
    if (gidx < N_NODES) cur_n[gidx] = 0;
    gbar(bar, 0, HG_BLOCKS);

    // ---- P1: exclusive scan (block 0: cnt_e->off_e; block 1: cnt_n->off_n)
    if (blockIdx.x < 2) {
        const int he_side = (blockIdx.x == 0);
        const int n = he_side ? NEDGE : N_NODES;
        const int* cnt = he_side ? cnt_e : cnt_n;
        int* off = he_side ? off_e : off_n;
        for (int i = tid; i < n; i += 256) smem[i] = cnt[i];
        __syncthreads();
        for (int st = 1; st < n; st <<= 1) {
            int v[16]; int nj = 0;
            for (int i = tid; i < n; i += 256) v[nj++] = (i >= st) ? smem[i - st] : 0;
            __syncthreads();
            nj = 0;
            for (int i = tid; i < n; i += 256) smem[i] += v[nj++];
            __syncthreads();
        }
        for (int i = tid; i < n; i += 256) off[i + 1] = smem[i];
        if (tid == 0) off[0] = 0;
    }
    gbar(bar, 1, HG_BLOCKS);

    // ---- P2: CSR fill
    if (gidx < NNZ_E) {
        int ni = nidx[gidx], he = hidx[gidx];
        int p = atomicAdd(&cur_e[he], 1);
        csr_e[off_e[he] + p] = ni;
        int q = atomicAdd(&cur_n[ni], 1);
        csr_n[off_n[ni] + q] = he;
    }
    gbar(bar, 2, HG_BLOCKS);

    // ---- P3: gather_e (4 hyperedges per block; 2 threads per dim)
    {
        int* ms = smem;                       // [256]
        float* red = (float*)(smem + 256);    // [128]
        const int half = tid >> 7, d = tid & 127;
        for (int he = blockIdx.x * 4; he < blockIdx.x * 4 + 4; ++he) {
            const int beg = off_e[he], end = off_e[he + 1];
            float acc = 0.f;
            for (int c = beg; c < end; c += 256) {
                int nl = min(256, end - c);
                if (tid < nl) ms[tid] = csr_e[c + tid];
                __syncthreads();
                for (int j = half; j < nl; j += 2) acc += h[(size_t)ms[j] * 128 + d];
                __syncthreads();
            }
            if (half) red[d] = acc;
            __syncthreads();
            if (!half) {
                float binv = (end > beg) ? 1.f / (float)(end - beg) : 0.f;
                float v = (acc + red[d]) * binv;
                u16 hi = f2b(v);
                e_hi[(size_t)he * 128 + d] = hi;
                e_lo[(size_t)he * 128 + d] = f2b(v - b2f_bits(hi));
            }
            __syncthreads();
        }
    }
    gbar(bar, 3, HG_BLOCKS);

    // ---- P4: Wh GEMM on 2048 aggregated rows (128 tile units; blocks >=128 idle)
    if (blockIdx.x < 128) {
        const int K = 128, NC = 128;
        const int w = tid >> 6, lane = tid & 63;
        const int qi = lane & 15, gi = lane >> 4;
        const int row0 = (blockIdx.x & 31) * 64 + w * 16;
        const int col0 = (blockIdx.x >> 5) * 32;
        const u16* Wlo = wp_h + (size_t)K * NC;
        f32x4 acc[2];
        acc[0] = (f32x4){0.f, 0.f, 0.f, 0.f};
        acc[1] = (f32x4){0.f, 0.f, 0.f, 0.f};
#pragma unroll 4
        for (int kc = 0; kc < K / 32; ++kc) {
            const int k0 = kc * 32;
            const size_t ao = (size_t)(row0 + qi) * K + k0 + gi * 8;
            bf16x8 ah = *(const bf16x8*)(e_hi + ao);
            bf16x8 al = *(const bf16x8*)(e_lo + ao);
#pragma unroll
            for (int c = 0; c < 2; ++c) {
                const size_t wo = ((size_t)(k0 / 8 + gi) * NC + col0 + c * 16 + qi) * 8;
                bf16x8 wh = *(const bf16x8*)(wp_h + wo);
                bf16x8 wl = *(const bf16x8*)(Wlo + wo);
                acc[c] = __builtin_amdgcn_mfma_f32_16x16x32_bf16(ah, wh, acc[c], 0, 0, 0);
                acc[c] = __builtin_amdgcn_mfma_f32_16x16x32_bf16(al, wh, acc[c], 0, 0, 0);
                acc[c] = __builtin_amdgcn_mfma_f32_16x16x32_bf16(ah, wl, acc[c], 0, 0, 0);
            }
        }
#pragma unroll
        for (int c = 0; c < 2; ++c) {
            const int col = col0 + c * 16 + qi;
#pragma unroll
            for (int r = 0; r < 4; ++r)
                e_sc[(size_t)(row0 + gi * 4 + r) * NC + col] = acc[c][r];
        }
    }
    gbar(bar, 4, HG_BLOCKS);

    // ---- P5: gather_n + bias + relu (8 nodes per block; 2 threads per dim)
    {
        int* ms = smem;
        float* red = (float*)(smem + 256);
        const int half = tid >> 7, d = tid & 127;
        for (int nn = blockIdx.x * 8; nn < blockIdx.x * 8 + 8; ++nn) {
            const int beg = off_n[nn], end = off_n[nn + 1];
            float acc = 0.f;
            for (int c = beg; c < end; c += 256) {
                int nl = min(256, end - c);
                if (tid < nl) ms[tid] = csr_n[c + tid];
                __syncthreads();
                for (int j = half; j < nl; j += 2) acc += e_sc[(size_t)ms[j] * 128 + d];
                __syncthreads();
            }
            if (half) red[d] = acc;
            __syncthreads();
            if (!half) {
                float dinv = (end > beg) ? 1.f / (float)(end - beg) : 0.f;
                float v = (acc + red[d]) * dinv + bh[d];
                out[(size_t)nn * 128 + d] = v > 0.f ? v : 0.f;
            }
            __syncthreads();
        }
    }
}

// ---------------------------------------------------------------------------
extern "C" void kernel_launch(void* const* d_in, const int* in_sizes, int n_in,
                              void* d_out, int out_size, void* d_ws, size_t ws_size,
                              hipStream_t stream) {
    (void)in_sizes; (void)n_in; (void)out_size; (void)ws_size;
    const float* x    = (const float*)d_in[0];
    const int*   edge = (const int*)  d_in[1];
    const float* Wq = (const float*)d_in[2];  const float* bq  = (const float*)d_in[3];
    const float* Wk = (const float*)d_in[4];  const float* bk  = (const float*)d_in[5];
    const float* Wv = (const float*)d_in[6];  const float* bv  = (const float*)d_in[7];
    const float* Wo = (const float*)d_in[8];  const float* bo  = (const float*)d_in[9];
    const float* g1 = (const float*)d_in[10]; const float* b1  = (const float*)d_in[11];
    const float* W1 = (const float*)d_in[12]; const float* bf1 = (const float*)d_in[13];
    const float* W2 = (const float*)d_in[14]; const float* bf2 = (const float*)d_in[15];
    const float* g2 = (const float*)d_in[16]; const float* b2  = (const float*)d_in[17];
    const float* Wh = (const float*)d_in[18]; const float* bh  = (const float*)d_in[19];
    float* out = (float*)d_out;

    // ---- workspace layout (fp32-word offsets), all live regions DISJOINT ----
    float* B = (float*)d_ws;
    float* h    = B;                          // [N,128] fp32
    u16*   h_hi = (u16*)(B + 524288);         // [N,128] bf16 (prep -> qkv L1 only)
    u16*   h_lo = (u16*)(B + 786432);
    u16*   qb   = (u16*)(B + 1048576);        // [H][N][64] bf16
    u16*   kb   = (u16*)(B + 1310720);
    u16*   vtb  = (u16*)(B + 1835008);        // [H][64][N] bf16
    float* op   = B + 2097152;                // [NSPLIT][N][128] fp32 -> end 6291456
    float* mlm  = B + 6291456;                // [NSPLIT][H][N]
    float* mll  = B + 6356992;                // -> end 6422528
    u16*   e_hi = (u16*)(B + 6946816);        // [NE,128] bf16
    u16*   e_lo = (u16*)(B + 7077888);
    float* e_sc = B + 7208960;                // [NE,128] fp32 -> end 7471104
    u16*   wp_q = (u16*)(B + 8519680);        // packs: 16384 w each (128x128)
    u16*   wp_k = (u16*)(B + 8536064);
    u16*   wp_v = (u16*)(B + 8552448);
    u16*   wp_o = (u16*)(B + 8568832);
    u16*   wp_h = (u16*)(B + 8585216);
    u16*   wp_1 = (u16*)(B + 8601600);        // 128x256: 32768 w
    u16*   wp_2 = (u16*)(B + 8634368);        // 256x128: 32768 w -> end 8667136
    int*   cur_e = (int*)(B + 9328640);       // [NE]
    int*   cur_n = (int*)(B + 9330688);       // [N]
    int*   off_e = (int*)(B + 9334784);       // [NE+1]
    int*   off_n = (int*)(B + 9336840);       // [N+1]
    int*   csr_e = (int*)(B + 9340944);       // [NNZ]
    int*   csr_n = (int*)(B + 9406480);       // [NNZ] -> end 9472016
    int*   cnt_e = (int*)(B + 9472016);       // [NE]   } cnt_e, cnt_n, bar contiguous
    int*   cnt_n = (int*)(B + 9474064);       // [N]    } (zeroed together by prep)
    int*   bar   = (int*)(B + 9478160);       // [16]
    int*   nidx  = (int*)(B + 9478176);       // [NNZ]
    int*   hidx  = (int*)(B + 9543712);       // [NNZ] -> end 9609248 (~38.4 MB)

    prep<<<2969, 256, 0, stream>>>(x, h, h_hi, h_lo,
                                   Wq, Wk, Wv, Wo, Wh, W1, W2,
                                   wp_q, wp_k, wp_v, wp_o, wp_h, wp_1, wp_2, cnt_e);

    qkv_mfma<<<dim3(64, 12), 256, 0, stream>>>(h_hi, h_lo, wp_q, wp_k, wp_v,
                                               bq, bk, bv, qb, kb, vtb);
    attn_mfma<<<dim3(N_NODES / 64, NHEAD, NSPLIT), 256, 0, stream>>>(qb, kb, vtb, op, mlm, mll);
    mega_layer<1><<<N_NODES / 16, 256, 0, stream>>>(op, mlm, mll, wp_o, bo, h, g1, b1,
                                                    wp_1, bf1, wp_2, bf2, g2, b2,
                                                    wp_q, wp_k, wp_v, bq, bk, bv,
                                                    qb, kb, vtb);
    attn_mfma<<<dim3(N_NODES / 64, NHEAD, NSPLIT), 256, 0, stream>>>(qb, kb, vtb, op, mlm, mll);
    mega_layer<0><<<N_NODES / 16, 256, 0, stream>>>(op, mlm, mll, wp_o, bo, h, g1, b1,
                                                    wp_1, bf1, wp_2, bf2, g2, b2,
                                                    nullptr, nullptr, nullptr,
                                                    nullptr, nullptr, nullptr,
                                                    nullptr, nullptr, nullptr);

    hyper_mega<<<HG_BLOCKS, 256, 0, stream>>>(edge, nidx, hidx, cnt_e, cnt_n,
                                              off_e, off_n, cur_e, cur_n,
                                              csr_e, csr_n, h, e_hi, e_lo,
                                              wp_h, e_sc, bh, out, bar);
}

// Round 13
// 253.456 us; speedup vs baseline: 2.7073x; 2.7073x over previous
//
#include <hip/hip_runtime.h>
#include <hip/hip_bf16.h>
#include <cstddef>

// Problem constants
#define N_NODES 4096
#define DIM     128
#define NHEAD   2
#define DHEAD   64
#define FFDIM   256
#define NEDGE   2048
#define NNZ_E   65536
#define NSPLIT  8

typedef __attribute__((ext_vector_type(8))) short bf16x8;   // 8 bf16 in 4 VGPRs
typedef __attribute__((ext_vector_type(4))) float f32x4;
typedef unsigned short u16;

__device__ __forceinline__ u16 f2b(float f) {               // rne fp32->bf16
    unsigned u = __float_as_uint(f);
    return (u16)((u + 0x7FFFu + ((u >> 16) & 1u)) >> 16);
}
__device__ __forceinline__ float b2f_bits(u16 h) {
    return __uint_as_float(((unsigned)h) << 16);
}

// ---------------------------------------------------------------------------
// prep: blocks [0,2048) split x; [2048,2944) pack weights; [2944,2969) zero cnt.
__global__ void prep(const float* __restrict__ x, float* __restrict__ h,
                     u16* __restrict__ hh, u16* __restrict__ hl,
                     const float* W0, const float* W1, const float* W2,
                     const float* W3, const float* W4, const float* W5,
                     const float* W6,
                     u16* P0, u16* P1, u16* P2, u16* P3, u16* P4, u16* P5, u16* P6,
                     int* __restrict__ cnt) {
    const int bx = blockIdx.x;
    if (bx < 2048) {
        int i = bx * 256 + threadIdx.x;
        float f = x[i];
        h[i] = f;
        u16 hi = f2b(f);
        hh[i] = hi;
        hl[i] = f2b(f - b2f_bits(hi));
        return;
    }
    if (bx >= 2944) {                 // zero cnt_e+cnt_n (6144 ints)
        int i = (bx - 2944) * 256 + threadIdx.x;
        if (i < NEDGE + N_NODES) cnt[i] = 0;
        return;
    }
    const int p = bx - 2048;
    const int sel = p >> 7;
    const float* W; u16* P; int K, NC;
    switch (sel) {
        case 0: W = W0; P = P0; K = 128; NC = 128; break;
        case 1: W = W1; P = P1; K = 128; NC = 128; break;
        case 2: W = W2; P = P2; K = 128; NC = 128; break;
        case 3: W = W3; P = P3; K = 128; NC = 128; break;
        case 4: W = W4; P = P4; K = 128; NC = 128; break;
        case 5: W = W5; P = P5; K = 128; NC = 256; break;
        default: W = W6; P = P6; K = 256; NC = 128; break;
    }
    int i = (p & 127) * 256 + threadIdx.x;
    if (i < K * NC) {
        int k = i / NC, n = i % NC;
        float f = W[i];
        u16 hb = f2b(f);
        size_t o = ((size_t)(k >> 3) * NC + n) * 8 + (k & 7);
        P[o] = hb;
        P[(size_t)K * NC + o] = f2b(f - b2f_bits(hb));
    }
}

// ---------------------------------------------------------------------------
// Generic split-bf16 MFMA GEMM (3-term ~fp32). Block 256 = 4 waves, tile 64x32.
template<int K, int NC>
__global__ __launch_bounds__(256) void gemm_mfma(const u16* __restrict__ Ah,
                                                 const u16* __restrict__ Al,
                                                 const u16* __restrict__ Wp,
                                                 float* __restrict__ C0) {
    const int tid = threadIdx.x, w = tid >> 6, lane = tid & 63;
    const int qi = lane & 15, gi = lane >> 4;
    const int row0 = blockIdx.x * 64 + w * 16;
    const int col0 = blockIdx.y * 32;
    const u16* Wlo = Wp + (size_t)K * NC;

    f32x4 acc[2];
    acc[0] = (f32x4){0.f, 0.f, 0.f, 0.f};
    acc[1] = (f32x4){0.f, 0.f, 0.f, 0.f};

#pragma unroll 4
    for (int kc = 0; kc < K / 32; ++kc) {
        const int k0 = kc * 32;
        const size_t ao = (size_t)(row0 + qi) * K + k0 + gi * 8;
        bf16x8 ah = *(const bf16x8*)(Ah + ao);
        bf16x8 al = *(const bf16x8*)(Al + ao);
#pragma unroll
        for (int c = 0; c < 2; ++c) {
            const size_t wo = ((size_t)(k0 / 8 + gi) * NC + col0 + c * 16 + qi) * 8;
            bf16x8 wh = *(const bf16x8*)(Wp + wo);
            bf16x8 wl = *(const bf16x8*)(Wlo + wo);
            acc[c] = __builtin_amdgcn_mfma_f32_16x16x32_bf16(ah, wh, acc[c], 0, 0, 0);
            acc[c] = __builtin_amdgcn_mfma_f32_16x16x32_bf16(al, wh, acc[c], 0, 0, 0);
            acc[c] = __builtin_amdgcn_mfma_f32_16x16x32_bf16(ah, wl, acc[c], 0, 0, 0);
        }
    }

#pragma unroll
    for (int c = 0; c < 2; ++c) {
        const int col = col0 + c * 16 + qi;
#pragma unroll
        for (int r = 0; r < 4; ++r) {
            const int grow = row0 + gi * 4 + r;
            C0[(size_t)grow * NC + col] = acc[c][r];
        }
    }
}

// ---------------------------------------------------------------------------
// Fused QKV GEMM (layer 1 only). Grid (64, 12): sel = y>>2, col0 = (y&3)*32.
__global__ __launch_bounds__(256) void qkv_mfma(const u16* __restrict__ Ah,
                                                const u16* __restrict__ Al,
                                                const u16* __restrict__ Wq,
                                                const u16* __restrict__ Wk,
                                                const u16* __restrict__ Wv,
                                                const float* __restrict__ bq,
                                                const float* __restrict__ bk,
                                                const float* __restrict__ bv,
                                                u16* __restrict__ qb,
                                                u16* __restrict__ kb,
                                                u16* __restrict__ vtb) {
    const int K = 128, NC = 128;
    const int tid = threadIdx.x, w = tid >> 6, lane = tid & 63;
    const int qi = lane & 15, gi = lane >> 4;
    const int row0 = blockIdx.x * 64 + w * 16;
    const int sel = blockIdx.y >> 2;
    const int col0 = (blockIdx.y & 3) * 32;
    const u16* Wp = (sel == 0) ? Wq : (sel == 1) ? Wk : Wv;
    const float* bias = (sel == 0) ? bq : (sel == 1) ? bk : bv;
    const u16* Wlo = Wp + (size_t)K * NC;

    f32x4 acc[2];
    acc[0] = (f32x4){0.f, 0.f, 0.f, 0.f};
    acc[1] = (f32x4){0.f, 0.f, 0.f, 0.f};

#pragma unroll 4
    for (int kc = 0; kc < K / 32; ++kc) {
        const int k0 = kc * 32;
        const size_t ao = (size_t)(row0 + qi) * K + k0 + gi * 8;
        bf16x8 ah = *(const bf16x8*)(Ah + ao);
        bf16x8 al = *(const bf16x8*)(Al + ao);
#pragma unroll
        for (int c = 0; c < 2; ++c) {
            const size_t wo = ((size_t)(k0 / 8 + gi) * NC + col0 + c * 16 + qi) * 8;
            bf16x8 wh = *(const bf16x8*)(Wp + wo);
            bf16x8 wl = *(const bf16x8*)(Wlo + wo);
            acc[c] = __builtin_amdgcn_mfma_f32_16x16x32_bf16(ah, wh, acc[c], 0, 0, 0);
            acc[c] = __builtin_amdgcn_mfma_f32_16x16x32_bf16(al, wh, acc[c], 0, 0, 0);
            acc[c] = __builtin_amdgcn_mfma_f32_16x16x32_bf16(ah, wl, acc[c], 0, 0, 0);
        }
    }

#pragma unroll
    for (int c = 0; c < 2; ++c) {
        const int col = col0 + c * 16 + qi;
        const int hh = col >> 6, d = col & 63;
        float bv_ = bias[col];
        if (sel < 2) {
            u16* dst = (sel == 0) ? qb : kb;
#pragma unroll
            for (int r = 0; r < 4; ++r) {
                const int grow = row0 + gi * 4 + r;
                dst[((size_t)hh * N_NODES + grow) * 64 + d] = f2b(acc[c][r] + bv_);
            }
        } else {
            const int grow0 = row0 + gi * 4;
            ushort4 pw;
            pw.x = f2b(acc[c][0] + bv_);
            pw.y = f2b(acc[c][1] + bv_);
            pw.z = f2b(acc[c][2] + bv_);
            pw.w = f2b(acc[c][3] + bv_);
            *(ushort4*)&vtb[((size_t)hh * 64 + d) * N_NODES + grow0] = pw;
        }
    }
}

// ---------------------------------------------------------------------------
// Split-K MFMA flash attention. Grid (N/64, H, NSPLIT); block 256 = 4 waves.
#define ROWP 72
__global__ __launch_bounds__(256) void attn_mfma(const u16* __restrict__ qb,
                                                 const u16* __restrict__ kb,
                                                 const u16* __restrict__ vtb,
                                                 float* __restrict__ op,
                                                 float* __restrict__ mlm,
                                                 float* __restrict__ mll) {
    __shared__ __align__(16) u16 k_s[64 * ROWP];
    __shared__ __align__(16) u16 vt_s[64 * ROWP];
    __shared__ __align__(16) u16 p_s[4][16 * ROWP];
    const int h = blockIdx.y;
    const int s = blockIdx.z;
    const int row0 = blockIdx.x * 64;
    const int tid = threadIdx.x;
    const int w = tid >> 6, lane = tid & 63;
    const int qi = lane & 15, gi = lane >> 4;
    const float CE = 0.18033688011f;   // 0.125 * log2(e)

    const u16* qrow = qb + ((size_t)h * N_NODES + row0 + w * 16 + qi) * 64 + gi * 8;
    bf16x8 qf0 = *(const bf16x8*)qrow;
    bf16x8 qf1 = *(const bf16x8*)(qrow + 32);

    f32x4 oc[4];
#pragma unroll
    for (int i = 0; i < 4; ++i) oc[i] = (f32x4){0.f, 0.f, 0.f, 0.f};
    float m_run = -INFINITY, l_run = 0.f;

    const u16* kbh = kb + (size_t)h * N_NODES * 64;
    const u16* vth = vtb + (size_t)h * 64 * N_NODES;

    for (int kt = s * (N_NODES / 64 / NSPLIT); kt < (s + 1) * (N_NODES / 64 / NSPLIT); ++kt) {
        const u16* ksrc = kbh + kt * 64 * 64;
#pragma unroll
        for (int i = 0; i < 2; ++i) {
            int c = tid + i * 256;
            int r = c >> 3, ss = c & 7;
            *(uint4*)&k_s[r * ROWP + ss * 8]  = *(const uint4*)(ksrc + c * 8);
            *(uint4*)&vt_s[r * ROWP + ss * 8] = *(const uint4*)(vth + (size_t)r * N_NODES + kt * 64 + ss * 8);
        }
        __syncthreads();

        f32x4 sc[4];
#pragma unroll
        for (int t = 0; t < 4; ++t) {
            const u16* krow = &k_s[(t * 16 + qi) * ROWP + gi * 8];
            bf16x8 ka0 = *(const bf16x8*)krow;
            bf16x8 ka1 = *(const bf16x8*)(krow + 32);
            f32x4 z = (f32x4){0.f, 0.f, 0.f, 0.f};
            z = __builtin_amdgcn_mfma_f32_16x16x32_bf16(ka0, qf0, z, 0, 0, 0);
            sc[t] = __builtin_amdgcn_mfma_f32_16x16x32_bf16(ka1, qf1, z, 0, 0, 0);
        }

        float smax = -INFINITY;
#pragma unroll
        for (int t = 0; t < 4; ++t)
            smax = fmaxf(smax, fmaxf(fmaxf(sc[t][0], sc[t][1]), fmaxf(sc[t][2], sc[t][3])));
        smax = fmaxf(smax, __shfl_xor(smax, 16));
        smax = fmaxf(smax, __shfl_xor(smax, 32));
        float mn = fmaxf(m_run, smax);
        float alpha = exp2f((m_run - mn) * CE);
        m_run = mn;
        float nb = mn * CE;
        float psum = 0.f;
#pragma unroll
        for (int t = 0; t < 4; ++t) {
            ushort4 pw;
            float p0 = exp2f(fmaf(sc[t][0], CE, -nb)); psum += p0; pw.x = f2b(p0);
            float p1 = exp2f(fmaf(sc[t][1], CE, -nb)); psum += p1; pw.y = f2b(p1);
            float p2 = exp2f(fmaf(sc[t][2], CE, -nb)); psum += p2; pw.z = f2b(p2);
            float p3 = exp2f(fmaf(sc[t][3], CE, -nb)); psum += p3; pw.w = f2b(p3);
            *(ushort4*)&p_s[w][qi * ROWP + t * 16 + gi * 4] = pw;
        }
        psum += __shfl_xor(psum, 16);
        psum += __shfl_xor(psum, 32);
        l_run = l_run * alpha + psum;

        float a0 = __shfl(alpha, gi * 4 + 0);
        float a1 = __shfl(alpha, gi * 4 + 1);
        float a2 = __shfl(alpha, gi * 4 + 2);
        float a3 = __shfl(alpha, gi * 4 + 3);
#pragma unroll
        for (int d = 0; d < 4; ++d) {
            oc[d][0] *= a0; oc[d][1] *= a1; oc[d][2] *= a2; oc[d][3] *= a3;
        }

        const u16* prow = &p_s[w][qi * ROWP];
        bf16x8 pa0 = *(const bf16x8*)(prow + gi * 8);
        bf16x8 pa1 = *(const bf16x8*)(prow + 32 + gi * 8);
#pragma unroll
        for (int d = 0; d < 4; ++d) {
            const u16* vrow = &vt_s[(d * 16 + qi) * ROWP + gi * 8];
            bf16x8 vb0 = *(const bf16x8*)vrow;
            bf16x8 vb1 = *(const bf16x8*)(vrow + 32);
            oc[d] = __builtin_amdgcn_mfma_f32_16x16x32_bf16(pa0, vb0, oc[d], 0, 0, 0);
            oc[d] = __builtin_amdgcn_mfma_f32_16x16x32_bf16(pa1, vb1, oc[d], 0, 0, 0);
        }
        __syncthreads();
    }

    float* opd = op + (size_t)s * N_NODES * 128;
#pragma unroll
    for (int d = 0; d < 4; ++d) {
        size_t cb = h * 64 + d * 16 + qi;
        opd[(size_t)(row0 + w * 16 + gi * 4 + 0) * 128 + cb] = oc[d][0];
        opd[(size_t)(row0 + w * 16 + gi * 4 + 1) * 128 + cb] = oc[d][1];
        opd[(size_t)(row0 + w * 16 + gi * 4 + 2) * 128 + cb] = oc[d][2];
        opd[(size_t)(row0 + w * 16 + gi * 4 + 3) * 128 + cb] = oc[d][3];
    }
    if (gi == 0) {
        size_t mi = (size_t)s * NHEAD * N_NODES + (size_t)h * N_NODES + row0 + w * 16 + qi;
        mlm[mi] = m_run;
        mll[mi] = l_run;
    }
}

// ---------------------------------------------------------------------------
// MEGA layer tail: combine -> Wo -> LN1 -> FF -> LN2 -> h (+ optional next QKV).
#define ROWA 136
#define ROWZ 264
#define ROWH 132
template<int DO_QKV>
__global__ __launch_bounds__(256) void mega_layer(
        const float* __restrict__ op, const float* __restrict__ mlm,
        const float* __restrict__ mll,
        const u16* __restrict__ wp_o, const float* __restrict__ bo,
        float* __restrict__ h,
        const float* __restrict__ g1, const float* __restrict__ b1,
        const u16* __restrict__ wp_1, const float* __restrict__ bf1,
        const u16* __restrict__ wp_2, const float* __restrict__ bf2,
        const float* __restrict__ g2, const float* __restrict__ b2,
        const u16* __restrict__ wp_q, const u16* __restrict__ wp_k,
        const u16* __restrict__ wp_v,
        const float* __restrict__ bq, const float* __restrict__ bk,
        const float* __restrict__ bv,
        u16* __restrict__ qb, u16* __restrict__ kb, u16* __restrict__ vtb) {
    __shared__ __align__(16) u16 zbuf[16 * ROWZ * 2];
    __shared__ __align__(16) u16 hp_hi[16 * ROWA];
    __shared__ __align__(16) u16 hp_lo[16 * ROWA];
    __shared__ float hln[16 * ROWH];
    __shared__ float ws_s[NSPLIT][32];
    __shared__ float Linv_s[32];
    __shared__ float wsum[4][16], wsq[4][16];
    const float CE = 0.18033688011f;
    const int tid = threadIdx.x, w = tid >> 6, lane = tid & 63;
    const int qi = lane & 15, gi = lane >> 4;
    const int row0 = blockIdx.x * 16;
    u16* a_hi = zbuf;
    u16* a_lo = zbuf + 16 * ROWA;
    u16* z_hi = zbuf;
    u16* z_lo = zbuf + 16 * ROWZ;

    if (tid < 32) {
        int r = tid >> 1, hd = tid & 1;
        size_t mb = (size_t)hd * N_NODES + row0 + r;
        float m[NSPLIT], l[NSPLIT], mx = -INFINITY;
#pragma unroll
        for (int s = 0; s < NSPLIT; ++s) {
            m[s] = mlm[mb + (size_t)s * NHEAD * N_NODES];
            l[s] = mll[mb + (size_t)s * NHEAD * N_NODES];
            mx = fmaxf(mx, m[s]);
        }
        float L = 0.f;
#pragma unroll
        for (int s = 0; s < NSPLIT; ++s) {
            float ws = exp2f((m[s] - mx) * CE);
            ws_s[s][tid] = ws;
            L += ws * l[s];
        }
        Linv_s[tid] = 1.f / L;
    }
    __syncthreads();

    for (int e = tid; e < 16 * 128; e += 256) {
        int r = e >> 7, c = e & 127, hd = c >> 6;
        size_t idx = (size_t)(row0 + r) * 128 + c;
        float O = 0.f;
#pragma unroll
        for (int s = 0; s < NSPLIT; ++s)
            O += ws_s[s][r * 2 + hd] * op[(size_t)s * N_NODES * 128 + idx];
        float v = O * Linv_s[r * 2 + hd];
        u16 hi = f2b(v);
        a_hi[r * ROWA + c] = hi;
        a_lo[r * ROWA + c] = f2b(v - b2f_bits(hi));
    }
    __syncthreads();

    {
        const u16* Wlo = wp_o + (size_t)128 * 128;
        f32x4 acc[2];
        acc[0] = (f32x4){0.f, 0.f, 0.f, 0.f};
        acc[1] = (f32x4){0.f, 0.f, 0.f, 0.f};
        const int col0 = w * 32;
#pragma unroll
        for (int kc = 0; kc < 4; ++kc) {
            const int k0 = kc * 32;
            bf16x8 ah = *(const bf16x8*)&a_hi[qi * ROWA + k0 + gi * 8];
            bf16x8 al = *(const bf16x8*)&a_lo[qi * ROWA + k0 + gi * 8];
#pragma unroll
            for (int c = 0; c < 2; ++c) {
                const size_t wo = ((size_t)(k0 / 8 + gi) * 128 + col0 + c * 16 + qi) * 8;
                bf16x8 wh = *(const bf16x8*)(wp_o + wo);
                bf16x8 wl = *(const bf16x8*)(Wlo + wo);
                acc[c] = __builtin_amdgcn_mfma_f32_16x16x32_bf16(ah, wh, acc[c], 0, 0, 0);
                acc[c] = __builtin_amdgcn_mfma_f32_16x16x32_bf16(al, wh, acc[c], 0, 0, 0);
                acc[c] = __builtin_amdgcn_mfma_f32_16x16x32_bf16(ah, wl, acc[c], 0, 0, 0);
            }
        }
        float y[2][4], rs[4], rq[4];
#pragma unroll
        for (int r = 0; r < 4; ++r) { rs[r] = 0.f; rq[r] = 0.f; }
#pragma unroll
        for (int c = 0; c < 2; ++c) {
            const int col = col0 + c * 16 + qi;
            float bv = bo[col];
#pragma unroll
            for (int r = 0; r < 4; ++r) {
                float v = acc[c][r] + bv + h[(size_t)(row0 + gi * 4 + r) * 128 + col];
                y[c][r] = v;
                rs[r] += v; rq[r] += v * v;
            }
        }
#pragma unroll
        for (int r = 0; r < 4; ++r)
            for (int msk = 1; msk < 16; msk <<= 1) {
                rs[r] += __shfl_xor(rs[r], msk);
                rq[r] += __shfl_xor(rq[r], msk);
            }
        if (qi == 0) {
#pragma unroll
            for (int r = 0; r < 4; ++r) { wsum[w][gi * 4 + r] = rs[r]; wsq[w][gi * 4 + r] = rq[r]; }
        }
        __syncthreads();
#pragma unroll
        for (int r = 0; r < 4; ++r) {
            const int lr = gi * 4 + r;
            float ts = wsum[0][lr] + wsum[1][lr] + wsum[2][lr] + wsum[3][lr];
            float tq = wsq[0][lr] + wsq[1][lr] + wsq[2][lr] + wsq[3][lr];
            float mean = ts * (1.f / 128.f);
            float var  = tq * (1.f / 128.f) - mean * mean;
            float rstd = rsqrtf(var + 1e-5f);
#pragma unroll
            for (int c = 0; c < 2; ++c) {
                const int col = col0 + c * 16 + qi;
                float yn = (y[c][r] - mean) * rstd * g1[col] + b1[col];
                hln[lr * ROWH + col] = yn;
                u16 hi = f2b(yn);
                hp_hi[lr * ROWA + col] = hi;
                hp_lo[lr * ROWA + col] = f2b(yn - b2f_bits(hi));
            }
        }
    }
    __syncthreads();

    {
        const u16* W1lo = wp_1 + (size_t)128 * 256;
        f32x4 acc1[4];
#pragma unroll
        for (int t = 0; t < 4; ++t) acc1[t] = (f32x4){0.f, 0.f, 0.f, 0.f};
#pragma unroll
        for (int kc = 0; kc < 4; ++kc) {
            const int k0 = kc * 32;
            bf16x8 ah = *(const bf16x8*)&hp_hi[qi * ROWA + k0 + gi * 8];
            bf16x8 al = *(const bf16x8*)&hp_lo[qi * ROWA + k0 + gi * 8];
#pragma unroll
            for (int t = 0; t < 4; ++t) {
                const size_t wo = ((size_t)(k0 / 8 + gi) * 256 + w * 64 + t * 16 + qi) * 8;
                bf16x8 wh = *(const bf16x8*)(wp_1 + wo);
                bf16x8 wl = *(const bf16x8*)(W1lo + wo);
                acc1[t] = __builtin_amdgcn_mfma_f32_16x16x32_bf16(ah, wh, acc1[t], 0, 0, 0);
                acc1[t] = __builtin_amdgcn_mfma_f32_16x16x32_bf16(al, wh, acc1[t], 0, 0, 0);
                acc1[t] = __builtin_amdgcn_mfma_f32_16x16x32_bf16(ah, wl, acc1[t], 0, 0, 0);
            }
        }
        __syncthreads();
#pragma unroll
        for (int t = 0; t < 4; ++t) {
            const int col = w * 64 + t * 16 + qi;
            float bv = bf1[col];
#pragma unroll
            for (int r = 0; r < 4; ++r) {
                float v = acc1[t][r] + bv;
                v = 1.f / (1.f + __expf(-v));
                u16 hi = f2b(v);
                const int zr = gi * 4 + r;
                z_hi[zr * ROWZ + col] = hi;
                z_lo[zr * ROWZ + col] = f2b(v - b2f_bits(hi));
            }
        }
    }
    __syncthreads();

    {
        const u16* W2lo = wp_2 + (size_t)256 * 128;
        f32x4 acc[2];
        acc[0] = (f32x4){0.f, 0.f, 0.f, 0.f};
        acc[1] = (f32x4){0.f, 0.f, 0.f, 0.f};
        const int col0 = w * 32;
#pragma unroll
        for (int kc = 0; kc < 8; ++kc) {
            const int k0 = kc * 32;
            bf16x8 ah = *(const bf16x8*)&z_hi[qi * ROWZ + k0 + gi * 8];
            bf16x8 al = *(const bf16x8*)&z_lo[qi * ROWZ + k0 + gi * 8];
#pragma unroll
            for (int c = 0; c < 2; ++c) {
                const size_t wo = ((size_t)(k0 / 8 + gi) * 128 + col0 + c * 16 + qi) * 8;
                bf16x8 wh = *(const bf16x8*)(wp_2 + wo);
                bf16x8 wl = *(const bf16x8*)(W2lo + wo);
                acc[c] = __builtin_amdgcn_mfma_f32_16x16x32_bf16(ah, wh, acc[c], 0, 0, 0);
                acc[c] = __builtin_amdgcn_mfma_f32_16x16x32_bf16(al, wh, acc[c], 0, 0, 0);
                acc[c] = __builtin_amdgcn_mfma_f32_16x16x32_bf16(ah, wl, acc[c], 0, 0, 0);
            }
        }
        float y[2][4], rs[4], rq[4];
#pragma unroll
        for (int r = 0; r < 4; ++r) { rs[r] = 0.f; rq[r] = 0.f; }
#pragma unroll
        for (int c = 0; c < 2; ++c) {
            const int col = col0 + c * 16 + qi;
            float bv = bf2[col];
#pragma unroll
            for (int r = 0; r < 4; ++r) {
                float v = acc[c][r] + bv + hln[(gi * 4 + r) * ROWH + col];
                y[c][r] = v;
                rs[r] += v; rq[r] += v * v;
            }
        }
#pragma unroll
        for (int r = 0; r < 4; ++r)
            for (int msk = 1; msk < 16; msk <<= 1) {
                rs[r] += __shfl_xor(rs[r], msk);
                rq[r] += __shfl_xor(rq[r], msk);
            }
        if (qi == 0) {
#pragma unroll
            for (int r = 0; r < 4; ++r) { wsum[w][gi * 4 + r] = rs[r]; wsq[w][gi * 4 + r] = rq[r]; }
        }
        __syncthreads();
#pragma unroll
        for (int r = 0; r < 4; ++r) {
            const int lr = gi * 4 + r;
            float ts = wsum[0][lr] + wsum[1][lr] + wsum[2][lr] + wsum[3][lr];
            float tq = wsq[0][lr] + wsq[1][lr] + wsq[2][lr] + wsq[3][lr];
            float mean = ts * (1.f / 128.f);
            float var  = tq * (1.f / 128.f) - mean * mean;
            float rstd = rsqrtf(var + 1e-5f);
#pragma unroll
            for (int c = 0; c < 2; ++c) {
                const int col = col0 + c * 16 + qi;
                float yn = (y[c][r] - mean) * rstd * g2[col] + b2[col];
                h[(size_t)(row0 + lr) * 128 + col] = yn;
                if (DO_QKV) {
                    u16 hi = f2b(yn);
                    hp_hi[lr * ROWA + col] = hi;
                    hp_lo[lr * ROWA + col] = f2b(yn - b2f_bits(hi));
                }
            }
        }
    }

    if (DO_QKV) {
        __syncthreads();
        const int col0 = w * 32;
#pragma unroll
        for (int sel = 0; sel < 3; ++sel) {
            const u16* Wp = (sel == 0) ? wp_q : (sel == 1) ? wp_k : wp_v;
            const float* bias = (sel == 0) ? bq : (sel == 1) ? bk : bv;
            const u16* Wlo = Wp + (size_t)128 * 128;
            f32x4 acc[2];
            acc[0] = (f32x4){0.f, 0.f, 0.f, 0.f};
            acc[1] = (f32x4){0.f, 0.f, 0.f, 0.f};
#pragma unroll
            for (int kc = 0; kc < 4; ++kc) {
                const int k0 = kc * 32;
                bf16x8 ah = *(const bf16x8*)&hp_hi[qi * ROWA + k0 + gi * 8];
                bf16x8 al = *(const bf16x8*)&hp_lo[qi * ROWA + k0 + gi * 8];
#pragma unroll
                for (int c = 0; c < 2; ++c) {
                    const size_t wo = ((size_t)(k0 / 8 + gi) * 128 + col0 + c * 16 + qi) * 8;
                    bf16x8 wh = *(const bf16x8*)(Wp + wo);
                    bf16x8 wl = *(const bf16x8*)(Wlo + wo);
                    acc[c] = __builtin_amdgcn_mfma_f32_16x16x32_bf16(ah, wh, acc[c], 0, 0, 0);
                    acc[c] = __builtin_amdgcn_mfma_f32_16x16x32_bf16(al, wh, acc[c], 0, 0, 0);
                    acc[c] = __builtin_amdgcn_mfma_f32_16x16x32_bf16(ah, wl, acc[c], 0, 0, 0);
                }
            }
#pragma unroll
            for (int c = 0; c < 2; ++c) {
                const int col = col0 + c * 16 + qi;
                const int hh = col >> 6, d = col & 63;
                float bv_ = bias[col];
                if (sel < 2) {
                    u16* dst = (sel == 0) ? qb : kb;
#pragma unroll
                    for (int r = 0; r < 4; ++r) {
                        const int grow = row0 + gi * 4 + r;
                        dst[((size_t)hh * N_NODES + grow) * 64 + d] = f2b(acc[c][r] + bv_);
                    }
                } else {
                    const int grow0 = row0 + gi * 4;
                    ushort4 pw;
                    pw.x = f2b(acc[c][0] + bv_);
                    pw.y = f2b(acc[c][1] + bv_);
                    pw.z = f2b(acc[c][2] + bv_);
                    pw.w = f2b(acc[c][3] + bv_);
                    *(ushort4*)&vtb[((size_t)hh * 64 + d) * N_NODES + grow0] = pw;
                }
            }
        }
    }
}

// ---------------------------------------------------------------------------
// Hypergraph CSR build + atomic-free gathers (separate dispatches — launch
// boundaries are ~50x cheaper than software grid barriers on this part, R12).
__global__ void hist_kernel(const int* __restrict__ edge_raw,
                            int* __restrict__ nidx, int* __restrict__ hidx,
                            int* __restrict__ cnt_e, int* __restrict__ cnt_n) {
    __shared__ int is64_s;
    if (threadIdx.x < 64) {
        int v = edge_raw[2 * threadIdx.x + 1];
        unsigned long long bal = __ballot(v != 0);
        if (threadIdx.x == 0) is64_s = (bal == 0ull) ? 1 : 0;
    }
    __syncthreads();
    const int is64 = is64_s;
    int i = blockIdx.x * 256 + threadIdx.x;
    if (i < NNZ_E) {
        int ni = (is64 ? edge_raw[2 * i]             : edge_raw[i])         & (N_NODES - 1);
        int he = (is64 ? edge_raw[2 * NNZ_E + 2 * i] : edge_raw[NNZ_E + i]) & (NEDGE - 1);
        nidx[i] = ni;
        hidx[i] = he;
        atomicAdd(&cnt_n[ni], 1);
        atomicAdd(&cnt_e[he], 1);
    }
}

__global__ __launch_bounds__(1024) void scan_only(const int* __restrict__ cnt_e,
                                                  const int* __restrict__ cnt_n,
                                                  int* __restrict__ off_e,
                                                  int* __restrict__ off_n,
                                                  int* __restrict__ cur_e,
                                                  int* __restrict__ cur_n) {
    __shared__ int s[N_NODES];
    const int he_side = (blockIdx.x == 0);
    const int n = he_side ? NEDGE : N_NODES;
    const int* cnt = he_side ? cnt_e : cnt_n;
    int* off = he_side ? off_e : off_n;
    int* cur = he_side ? cur_e : cur_n;
    for (int i = threadIdx.x; i < n; i += 1024) s[i] = cnt[i];
    __syncthreads();
    for (int st = 1; st < n; st <<= 1) {
        int v[4]; int nj = 0;
        for (int i = threadIdx.x; i < n; i += 1024) v[nj++] = (i >= st) ? s[i - st] : 0;
        __syncthreads();
        nj = 0;
        for (int i = threadIdx.x; i < n; i += 1024) s[i] += v[nj++];
        __syncthreads();
    }
    for (int i = threadIdx.x; i < n; i += 1024) { off[i + 1] = s[i]; cur[i] = 0; }
    if (threadIdx.x == 0) off[0] = 0;
}

__global__ void fill_csr(const int* __restrict__ nidx, const int* __restrict__ hidx,
                         const int* __restrict__ off_e, const int* __restrict__ off_n,
                         int* __restrict__ cur_e, int* __restrict__ cur_n,
                         int* __restrict__ csr_e, int* __restrict__ csr_n) {
    int i = blockIdx.x * 256 + threadIdx.x;
    if (i < NNZ_E) {
        int ni = nidx[i], he = hidx[i];
        int p = atomicAdd(&cur_e[he], 1);
        csr_e[off_e[he] + p] = ni;
        int q = atomicAdd(&cur_n[ni], 1);
        csr_n[off_n[ni] + q] = he;
    }
}

__global__ __launch_bounds__(128) void gather_e(const int* __restrict__ off_e,
                                                const int* __restrict__ csr_e,
                                                const float* __restrict__ h,
                                                u16* __restrict__ ehi,
                                                u16* __restrict__ elo) {
    __shared__ int ms[128];
    const int he = blockIdx.x, d = threadIdx.x;
    const int beg = off_e[he], end = off_e[he + 1];
    float acc = 0.f;
    for (int c = beg; c < end; c += 128) {
        int nl = min(128, end - c);
        if (d < nl) ms[d] = csr_e[c + d];
        __syncthreads();
        for (int j = 0; j < nl; ++j) acc += h[(size_t)ms[j] * 128 + d];
        __syncthreads();
    }
    float binv = (end > beg) ? 1.f / (float)(end - beg) : 0.f;
    float v = acc * binv;
    u16 hi = f2b(v);
    ehi[(size_t)he * 128 + d] = hi;
    elo[(size_t)he * 128 + d] = f2b(v - b2f_bits(hi));
}

__global__ __launch_bounds__(128) void gather_n(const int* __restrict__ off_n,
                                                const int* __restrict__ csr_n,
                                                const float* __restrict__ e_sc,
                                                const float* __restrict__ bh,
                                                float* __restrict__ out) {
    __shared__ int ms[128];
    const int nn = blockIdx.x, d = threadIdx.x;
    const int beg = off_n[nn], end = off_n[nn + 1];
    float acc = 0.f;
    for (int c = beg; c < end; c += 128) {
        int nl = min(128, end - c);
        if (d < nl) ms[d] = csr_n[c + d];
        __syncthreads();
        for (int j = 0; j < nl; ++j) acc += e_sc[(size_t)ms[j] * 128 + d];
        __syncthreads();
    }
    float dinv = (end > beg) ? 1.f / (float)(end - beg) : 0.f;
    float v = acc * dinv + bh[d];
    out[(size_t)nn * 128 + d] = v > 0.f ? v : 0.f;
}

// ---------------------------------------------------------------------------
extern "C" void kernel_launch(void* const* d_in, const int* in_sizes, int n_in,
                              void* d_out, int out_size, void* d_ws, size_t ws_size,
                              hipStream_t stream) {
    (void)in_sizes; (void)n_in; (void)out_size; (void)ws_size;
    const float* x    = (const float*)d_in[0];
    const int*   edge = (const int*)  d_in[1];
    const float* Wq = (const float*)d_in[2];  const float* bq  = (const float*)d_in[3];
    const float* Wk = (const float*)d_in[4];  const float* bk  = (const float*)d_in[5];
    const float* Wv = (const float*)d_in[6];  const float* bv  = (const float*)d_in[7];
    const float* Wo = (const float*)d_in[8];  const float* bo  = (const float*)d_in[9];
    const float* g1 = (const float*)d_in[10]; const float* b1  = (const float*)d_in[11];
    const float* W1 = (const float*)d_in[12]; const float* bf1 = (const float*)d_in[13];
    const float* W2 = (const float*)d_in[14]; const float* bf2 = (const float*)d_in[15];
    const float* g2 = (const float*)d_in[16]; const float* b2  = (const float*)d_in[17];
    const float* Wh = (const float*)d_in[18]; const float* bh  = (const float*)d_in[19];
    float* out = (float*)d_out;

    // ---- workspace layout (fp32-word offsets), all live regions DISJOINT ----
    float* B = (float*)d_ws;
    float* h    = B;                          // [N,128] fp32
    u16*   h_hi = (u16*)(B + 524288);         // [N,128] bf16 (prep -> qkv L1 only)
    u16*   h_lo = (u16*)(B + 786432);
    u16*   qb   = (u16*)(B + 1048576);        // [H][N][64] bf16
    u16*   kb   = (u16*)(B + 1310720);
    u16*   vtb  = (u16*)(B + 1835008);        // [H][64][N] bf16
    float* op   = B + 2097152;                // [NSPLIT][N][128] fp32 -> end 6291456
    float* mlm  = B + 6291456;                // [NSPLIT][H][N]
    float* mll  = B + 6356992;                // -> end 6422528
    u16*   e_hi = (u16*)(B + 6946816);        // [NE,128] bf16
    u16*   e_lo = (u16*)(B + 7077888);
    float* e_sc = B + 7208960;                // [NE,128] fp32 -> end 7471104
    u16*   wp_q = (u16*)(B + 8519680);        // packs: 16384 w each (128x128)
    u16*   wp_k = (u16*)(B + 8536064);
    u16*   wp_v = (u16*)(B + 8552448);
    u16*   wp_o = (u16*)(B + 8568832);
    u16*   wp_h = (u16*)(B + 8585216);
    u16*   wp_1 = (u16*)(B + 8601600);        // 128x256: 32768 w
    u16*   wp_2 = (u16*)(B + 8634368);        // 256x128: 32768 w -> end 8667136
    int*   cur_e = (int*)(B + 9328640);       // [NE]
    int*   cur_n = (int*)(B + 9330688);       // [N]
    int*   off_e = (int*)(B + 9334784);       // [NE+1]
    int*   off_n = (int*)(B + 9336840);       // [N+1]
    int*   csr_e = (int*)(B + 9340944);       // [NNZ]
    int*   csr_n = (int*)(B + 9406480);       // [NNZ] -> end 9472016
    int*   cnt_e = (int*)(B + 9472016);       // [NE]  (cnt_e+cnt_n contiguous)
    int*   cnt_n = (int*)(B + 9474064);       // [N]   -> end 9478160
    int*   nidx  = (int*)(B + 9478160);       // [NNZ]
    int*   hidx  = (int*)(B + 9543696);       // [NNZ] -> end 9609232 (~38.4 MB)

    prep<<<2969, 256, 0, stream>>>(x, h, h_hi, h_lo,
                                   Wq, Wk, Wv, Wo, Wh, W1, W2,
                                   wp_q, wp_k, wp_v, wp_o, wp_h, wp_1, wp_2, cnt_e);

    qkv_mfma<<<dim3(64, 12), 256, 0, stream>>>(h_hi, h_lo, wp_q, wp_k, wp_v,
                                               bq, bk, bv, qb, kb, vtb);
    attn_mfma<<<dim3(N_NODES / 64, NHEAD, NSPLIT), 256, 0, stream>>>(qb, kb, vtb, op, mlm, mll);
    mega_layer<1><<<N_NODES / 16, 256, 0, stream>>>(op, mlm, mll, wp_o, bo, h, g1, b1,
                                                    wp_1, bf1, wp_2, bf2, g2, b2,
                                                    wp_q, wp_k, wp_v, bq, bk, bv,
                                                    qb, kb, vtb);
    attn_mfma<<<dim3(N_NODES / 64, NHEAD, NSPLIT), 256, 0, stream>>>(qb, kb, vtb, op, mlm, mll);
    mega_layer<0><<<N_NODES / 16, 256, 0, stream>>>(op, mlm, mll, wp_o, bo, h, g1, b1,
                                                    wp_1, bf1, wp_2, bf2, g2, b2,
                                                    nullptr, nullptr, nullptr,
                                                    nullptr, nullptr, nullptr,
                                                    nullptr, nullptr, nullptr);

    // hypergraph: histogram -> scan -> CSR fill -> gather_e -> Wh GEMM -> gather_n
    hist_kernel<<<NNZ_E / 256, 256, 0, stream>>>(edge, nidx, hidx, cnt_e, cnt_n);
    scan_only<<<2, 1024, 0, stream>>>(cnt_e, cnt_n, off_e, off_n, cur_e, cur_n);
    fill_csr<<<NNZ_E / 256, 256, 0, stream>>>(nidx, hidx, off_e, off_n, cur_e, cur_n, csr_e, csr_n);
    gather_e<<<NEDGE, 128, 0, stream>>>(off_e, csr_e, h, e_hi, e_lo);
    gemm_mfma<128, 128><<<dim3(NEDGE / 64, 4), 256, 0, stream>>>(e_hi, e_lo, wp_h, e_sc);
    gather_n<<<N_NODES, 128, 0, stream>>>(off_n, csr_n, e_sc, bh, out);
}